// Round 2
// baseline (135.836 us; speedup 1.0000x reference)
//
#include <hip/hip_runtime.h>

// Problem constants (fixed by reference): S=256, B=64, D=1024, T=64
#define SLEN 256
#define NB   64
#define ND   1024
#define NT   64
// BOS=0, EOS=1, PAD=2

typedef float f32x4  __attribute__((ext_vector_type(4)));
typedef short bf16x8 __attribute__((ext_vector_type(8)));   // 8 bf16 in 4 VGPRs

__device__ __forceinline__ unsigned cvt_pk_bf16(float lo, float hi) {
  unsigned r;
  asm("v_cvt_pk_bf16_f32 %0, %1, %2" : "=v"(r) : "v"(lo), "v"(hi));
  return r;
}

__device__ __forceinline__ bf16x8 pack_bf16x8(f32x4 a, f32x4 b) {
  union { unsigned u[4]; bf16x8 v; } r;
  r.u[0] = cvt_pk_bf16(a.x, a.y);
  r.u[1] = cvt_pk_bf16(a.z, a.w);
  r.u[2] = cvt_pk_bf16(b.x, b.y);
  r.u[3] = cvt_pk_bf16(b.z, b.w);
  return r.v;
}

// ---------------------------------------------------------------------------
// Kernel 0: W[t][k] f32 -> bf16 frag-stream layout (B-frag of 16x16x32).
// ---------------------------------------------------------------------------
__global__ __launch_bounds__(256) void prep_w(const float* __restrict__ W,
                                              unsigned short* __restrict__ Wb3) {
  int o  = blockIdx.x * 256 + threadIdx.x;          // 0..65535
  int e  = o & 7;
  int l  = (o >> 3) & 63;
  int f  = (o >> 9) & 3;
  int k0 = o >> 11;
  int t  = f * 16 + (l & 15);
  int k  = k0 * 32 + ((l >> 4) << 3) + e;
  unsigned u = __float_as_uint(W[t * ND + k]);
  Wb3[o] = (unsigned short)((u + 0x7FFFu + ((u >> 16) & 1u)) >> 16);  // RNE
}

// ---------------------------------------------------------------------------
// Kernel 1: xbuf[r][t] = exp( features[r]·W[t] + b[t] ),  r = s*B + b flat.
// MFMA GEMM; epilogue applies bias + exp so the recursion kernel never
// executes a transcendental on its critical path.
// ---------------------------------------------------------------------------
__global__ __launch_bounds__(256) void emit_gemm(const float* __restrict__ F,
                                                 const unsigned short* __restrict__ Wb3,
                                                 const float* __restrict__ bias,
                                                 float* __restrict__ xbuf) {
  const int lane = threadIdx.x & 63;
  const int wv   = (blockIdx.x * 256 + threadIdx.x) >> 6;  // 0..1023
  const int r0   = wv * 16;
  const int m    = lane & 15;
  const int kg   = lane >> 4;
  const float* arow = F + (size_t)(r0 + m) * ND + kg * 8;
  const bf16x8* bptr = reinterpret_cast<const bf16x8*>(Wb3) + lane;

  f32x4 acc0 = {0.f, 0.f, 0.f, 0.f};
  f32x4 acc1 = acc0, acc2 = acc0, acc3 = acc0;

  for (int g = 0; g < 32; g += 4) {
    f32x4  a[4][2];
    bf16x8 bb[4][4];
#pragma unroll
    for (int qq = 0; qq < 4; ++qq) {
      a[qq][0] = *(const f32x4*)(arow + (g + qq) * 32);
      a[qq][1] = *(const f32x4*)(arow + (g + qq) * 32 + 4);
#pragma unroll
      for (int f = 0; f < 4; ++f) bb[qq][f] = bptr[((g + qq) * 4 + f) * 64];
    }
#pragma unroll
    for (int qq = 0; qq < 4; ++qq) {
      bf16x8 af = pack_bf16x8(a[qq][0], a[qq][1]);
      acc0 = __builtin_amdgcn_mfma_f32_16x16x32_bf16(af, bb[qq][0], acc0, 0, 0, 0);
      acc1 = __builtin_amdgcn_mfma_f32_16x16x32_bf16(af, bb[qq][1], acc1, 0, 0, 0);
      acc2 = __builtin_amdgcn_mfma_f32_16x16x32_bf16(af, bb[qq][2], acc2, 0, 0, 0);
      acc3 = __builtin_amdgcn_mfma_f32_16x16x32_bf16(af, bb[qq][3], acc3, 0, 0, 0);
    }
  }

  const float bv0 = bias[m], bv1 = bias[16 + m], bv2 = bias[32 + m], bv3 = bias[48 + m];
  float* op = xbuf + (size_t)(r0 + kg * 4) * NT + m;
#pragma unroll
  for (int r = 0; r < 4; ++r) {
    op[r * NT +  0] = __expf(acc0[r] + bv0);
    op[r * NT + 16] = __expf(acc1[r] + bv1);
    op[r * NT + 32] = __expf(acc2[r] + bv2);
    op[r * NT + 48] = __expf(acc3[r] + bv3);
  }
}

// ---------------------------------------------------------------------------
// Kernel 2: CRF forward recursion via MFMA, 16 batches per wave, 4 waves.
// State alpha^T (64 tags x 16 batches) lives in 4 f32x4 accs in D-layout:
//   lane (q=l>>4, c=l&15): acc[mt][r] = alpha[j = 16mt+4q+r][batch c].
// Step: w = alpha ⊙ x_t  (bf16)  ->  alpha' = E^T · w  (8 MFMAs, E^T resident
// in 8 bf16 A-frags). D->B layout conversion is 4x {permlane32_swap +
// permlane16_swap} (derivation: batch stays in lane&15; word (kf,p) at dest
// group q comes from pk[2kf + (q>>1)][p] of source groups 2(q&1), 2(q&1)+1).
// Renorm by exact power of 2 every 8 steps; capture alpha[EOS] at t==L-1.
// ---------------------------------------------------------------------------
__device__ __forceinline__ bf16x8 make_et(const float* __restrict__ trans,
                                          int q, int c, int mt, int kf) {
  float v[8];
#pragma unroll
  for (int e = 0; e < 8; ++e)
    v[e] = __expf(trans[(32 * kf + 8 * q + e) * NT + 16 * mt + c]);
  union { unsigned u[4]; bf16x8 b; } r;
  r.u[0] = cvt_pk_bf16(v[0], v[1]);
  r.u[1] = cvt_pk_bf16(v[2], v[3]);
  r.u[2] = cvt_pk_bf16(v[4], v[5]);
  r.u[3] = cvt_pk_bf16(v[6], v[7]);
  return r.b;
}

__global__ __launch_bounds__(64) void crf_fwd_mfma(const float* __restrict__ xbuf,
                                                   const float* __restrict__ trans,
                                                   const int*   __restrict__ tags,
                                                   const int*   __restrict__ seq_lens,
                                                   float* __restrict__ partials) {
  const int l = threadIdx.x;
  const int q = l >> 4, c = l & 15;
  const int bglob = blockIdx.x * 16 + c;

  const int L   = seq_lens[bglob];     // in [2, 256]
  const int Lm1 = L - 1;
  int maxL = L;                        // max over the wave's 16 batches
  maxL = max(maxL, __shfl_xor(maxL, 1, 64));
  maxL = max(maxL, __shfl_xor(maxL, 2, 64));
  maxL = max(maxL, __shfl_xor(maxL, 4, 64));
  maxL = max(maxL, __shfl_xor(maxL, 8, 64));

  // ---- gold path score (q-lanes split the steps of batch c) ----
  float gold = 0.f;
  for (int s = q; s < L; s += 4) {
    int tg = tags[s * NB + bglob];
    int nx = (s + 1 < SLEN) ? tags[(s + 1) * NB + bglob] : 2;
    gold += __logf(xbuf[(size_t)(s * NB + bglob) * NT + tg]) + trans[tg * NT + nx];
  }
  gold += __shfl_xor(gold, 16, 64);
  gold += __shfl_xor(gold, 32, 64);

  // ---- E^T fragments (A-operand, resident) ----
  bf16x8 et00 = make_et(trans, q, c, 0, 0), et01 = make_et(trans, q, c, 0, 1);
  bf16x8 et10 = make_et(trans, q, c, 1, 0), et11 = make_et(trans, q, c, 1, 1);
  bf16x8 et20 = make_et(trans, q, c, 2, 0), et21 = make_et(trans, q, c, 2, 1);
  bf16x8 et30 = make_et(trans, q, c, 3, 0), et31 = make_et(trans, q, c, 3, 1);

  // ---- init: alpha0[j] = exp(trans[0][j]); logZ = emit[0,b,BOS] = log x[0,b,0]
  f32x4 acc0, acc1, acc2, acc3;
  {
    const float* tr0 = trans + 4 * q;
    f32x4 t0 = *(const f32x4*)(tr0 +  0);
    f32x4 t1 = *(const f32x4*)(tr0 + 16);
    f32x4 t2 = *(const f32x4*)(tr0 + 32);
    f32x4 t3 = *(const f32x4*)(tr0 + 48);
    acc0.x = __expf(t0.x); acc0.y = __expf(t0.y); acc0.z = __expf(t0.z); acc0.w = __expf(t0.w);
    acc1.x = __expf(t1.x); acc1.y = __expf(t1.y); acc1.z = __expf(t1.z); acc1.w = __expf(t1.w);
    acc2.x = __expf(t2.x); acc2.y = __expf(t2.y); acc2.z = __expf(t2.z); acc2.w = __expf(t2.w);
    acc3.x = __expf(t3.x); acc3.y = __expf(t3.y); acc3.z = __expf(t3.z); acc3.w = __expf(t3.w);
  }
  float logZ = __logf(xbuf[(size_t)bglob * NT]);

  // ---- x prefetch pipeline (2 deep); lane reads 4 f32x4 per step ----
  const float* xlane = xbuf + (size_t)bglob * NT + 4 * q;   // + t*4096 + mt*16
  f32x4 xA0, xA1, xA2, xA3, xB0, xB1, xB2, xB3;
  {
    const float* p1 = xlane + (size_t)1 * NB * NT;
    xA0 = *(const f32x4*)(p1);      xA1 = *(const f32x4*)(p1 + 16);
    xA2 = *(const f32x4*)(p1 + 32); xA3 = *(const f32x4*)(p1 + 48);
    const float* p2 = xlane + (size_t)2 * NB * NT;
    xB0 = *(const f32x4*)(p2);      xB1 = *(const f32x4*)(p2 + 16);
    xB2 = *(const f32x4*)(p2 + 32); xB3 = *(const f32x4*)(p2 + 48);
  }

  float Cap = 1.f, Zcap = 0.f;

#define SWAPQ(A, B) do {                                                  \
    asm("v_permlane32_swap_b32 %0, %1" : "+v"(A), "+v"(B));               \
    asm("v_permlane16_swap_b32 %0, %1" : "+v"(A), "+v"(B));               \
  } while (0)

#define STEP(X0, X1, X2, X3, T) do {                                      \
    if (((T) & 7) == 0) {  /* exact pow2 renorm, batch-uniform */         \
      float bc = __shfl(acc0.x, c, 64);                                   \
      int ex = (int)((__float_as_uint(bc) >> 23) & 255u) - 127;           \
      float sc = __uint_as_float((unsigned)(127 - ex) << 23);             \
      X0 *= sc; X1 *= sc; X2 *= sc; X3 *= sc;                             \
      logZ += (float)ex * 0.6931471805599453f;                            \
    }                                                                     \
    f32x4 w0 = acc0 * X0, w1 = acc1 * X1, w2 = acc2 * X2, w3 = acc3 * X3; \
    unsigned p00 = cvt_pk_bf16(w0.x, w0.y), p01 = cvt_pk_bf16(w0.z, w0.w); \
    unsigned p10 = cvt_pk_bf16(w1.x, w1.y), p11 = cvt_pk_bf16(w1.z, w1.w); \
    unsigned p20 = cvt_pk_bf16(w2.x, w2.y), p21 = cvt_pk_bf16(w2.z, w2.w); \
    unsigned p30 = cvt_pk_bf16(w3.x, w3.y), p31 = cvt_pk_bf16(w3.z, w3.w); \
    SWAPQ(p00, p10); SWAPQ(p01, p11); SWAPQ(p20, p30); SWAPQ(p21, p31);   \
    union { unsigned u[4]; bf16x8 v; } Bf0, Bf1;                          \
    Bf0.u[0] = p00; Bf0.u[1] = p01; Bf0.u[2] = p10; Bf0.u[3] = p11;       \
    Bf1.u[0] = p20; Bf1.u[1] = p21; Bf1.u[2] = p30; Bf1.u[3] = p31;       \
    const f32x4 zz = {0.f, 0.f, 0.f, 0.f};                                \
    acc0 = __builtin_amdgcn_mfma_f32_16x16x32_bf16(et00, Bf0.v, zz,   0, 0, 0); \
    acc0 = __builtin_amdgcn_mfma_f32_16x16x32_bf16(et01, Bf1.v, acc0, 0, 0, 0); \
    acc1 = __builtin_amdgcn_mfma_f32_16x16x32_bf16(et10, Bf0.v, zz,   0, 0, 0); \
    acc1 = __builtin_amdgcn_mfma_f32_16x16x32_bf16(et11, Bf1.v, acc1, 0, 0, 0); \
    acc2 = __builtin_amdgcn_mfma_f32_16x16x32_bf16(et20, Bf0.v, zz,   0, 0, 0); \
    acc2 = __builtin_amdgcn_mfma_f32_16x16x32_bf16(et21, Bf1.v, acc2, 0, 0, 0); \
    acc3 = __builtin_amdgcn_mfma_f32_16x16x32_bf16(et30, Bf0.v, zz,   0, 0, 0); \
    acc3 = __builtin_amdgcn_mfma_f32_16x16x32_bf16(et31, Bf1.v, acc3, 0, 0, 0); \
    { const float* pf = xlane + (size_t)((T) + 2) * (NB * NT);            \
      X0 = *(const f32x4*)(pf);      X1 = *(const f32x4*)(pf + 16);       \
      X2 = *(const f32x4*)(pf + 32); X3 = *(const f32x4*)(pf + 48); }     \
    bool cap = ((T) == Lm1);                                              \
    Cap  = cap ? acc0.y : Cap;   /* j = 4q+1 -> EOS at q==0 */            \
    Zcap = cap ? logZ   : Zcap;                                           \
  } while (0)

  int t = 1;
  for (; t + 1 < maxL; t += 2) {
    STEP(xA0, xA1, xA2, xA3, t);
    STEP(xB0, xB1, xB2, xB3, t + 1);
  }
  if (t < maxL) STEP(xA0, xA1, xA2, xA3, t);

#undef STEP
#undef SWAPQ

  if (l < 16) partials[bglob] = Zcap + __logf(Cap) - gold;
}

// ---------------------------------------------------------------------------
// Kernel 3: out[0] = sum_b partials[b]
// ---------------------------------------------------------------------------
__global__ __launch_bounds__(64) void final_reduce(const float* __restrict__ partials,
                                                   float* __restrict__ out) {
  float v = partials[threadIdx.x];
#pragma unroll
  for (int off = 32; off; off >>= 1) v += __shfl_xor(v, off, 64);
  if (threadIdx.x == 0) out[0] = v;
}

extern "C" void kernel_launch(void* const* d_in, const int* in_sizes, int n_in,
                              void* d_out, int out_size, void* d_ws, size_t ws_size,
                              hipStream_t stream) {
  const float* F     = (const float*)d_in[0];   // features (S,B,D) f32
  const int*   tags  = (const int*)  d_in[1];   // (S,B) i32
  const int*   seq   = (const int*)  d_in[2];   // (B,) i32
  const float* W     = (const float*)d_in[3];   // (T,D) f32
  const float* bias  = (const float*)d_in[4];   // (T,) f32
  const float* trans = (const float*)d_in[5];   // (T,T) f32
  float* out = (float*)d_out;

  char* ws = (char*)d_ws;
  // xbuf: 256 rows used + 2 rows prefetch-overrun slack => 4.25 MiB region
  float*          xbuf     = (float*)ws;
  unsigned short* Wb3      = (unsigned short*)(ws + 4456448);            // 4.25 MiB
  float*          partials = (float*)(ws + 4456448 + 131072);

  prep_w      <<<256, 256, 0, stream>>>(W, Wb3);
  emit_gemm   <<<256, 256, 0, stream>>>(F, Wb3, bias, xbuf);
  crf_fwd_mfma<<<4,    64, 0, stream>>>(xbuf, trans, tags, seq, partials);
  final_reduce<<<1,    64, 0, stream>>>(partials, out);
}

// Round 3
// 58.728 us; speedup vs baseline: 2.3130x; 2.3130x over previous
//
#include <hip/hip_runtime.h>

// Problem constants (fixed by reference): S=256, B=64, D=1024, T=64
#define SLEN 256
#define NB   64
#define ND   1024
#define NT   64
// BOS=0, EOS=1, PAD=2

typedef float f32x4  __attribute__((ext_vector_type(4)));
typedef short bf16x8 __attribute__((ext_vector_type(8)));
typedef unsigned int u32;
typedef u32 u32x4 __attribute__((ext_vector_type(4)));

__device__ __forceinline__ u32 cvt_pk_bf16(float lo, float hi) {
  u32 r;
  asm("v_cvt_pk_bf16_f32 %0, %1, %2" : "=v"(r) : "v"(lo), "v"(hi));
  return r;
}

__device__ __forceinline__ bf16x8 pack_bf16x8(f32x4 a, f32x4 b) {
  union { u32 u[4]; bf16x8 v; } r;
  r.u[0] = cvt_pk_bf16(a.x, a.y);
  r.u[1] = cvt_pk_bf16(a.z, a.w);
  r.u[2] = cvt_pk_bf16(b.x, b.y);
  r.u[3] = cvt_pk_bf16(b.z, b.w);
  return r.v;
}

// ---------------------------------------------------------------------------
// Kernel 0: W[t][k] f32 -> bf16 frag-stream layout (B-frag of 16x16x32).
// ---------------------------------------------------------------------------
__global__ __launch_bounds__(256) void prep_w(const float* __restrict__ W,
                                              unsigned short* __restrict__ Wb3) {
  int o  = blockIdx.x * 256 + threadIdx.x;          // 0..65535
  int e  = o & 7;
  int l  = (o >> 3) & 63;
  int f  = (o >> 9) & 3;
  int k0 = o >> 11;
  int t  = f * 16 + (l & 15);
  int k  = k0 * 32 + ((l >> 4) << 3) + e;
  unsigned u = __float_as_uint(W[t * ND + k]);
  Wb3[o] = (unsigned short)((u + 0x7FFFu + ((u >> 16) & 1u)) >> 16);  // RNE
}

// ---------------------------------------------------------------------------
// Kernel 1: xbuf[r][t] = exp( features[r]·W[t] + b[t] ),  r = s*B + b flat.
// (unchanged from R1/R2 — proven)
// ---------------------------------------------------------------------------
__global__ __launch_bounds__(256) void emit_gemm(const float* __restrict__ F,
                                                 const unsigned short* __restrict__ Wb3,
                                                 const float* __restrict__ bias,
                                                 float* __restrict__ xbuf) {
  const int lane = threadIdx.x & 63;
  const int wv   = (blockIdx.x * 256 + threadIdx.x) >> 6;  // 0..1023
  const int r0   = wv * 16;
  const int m    = lane & 15;
  const int kg   = lane >> 4;
  const float* arow = F + (size_t)(r0 + m) * ND + kg * 8;
  const bf16x8* bptr = reinterpret_cast<const bf16x8*>(Wb3) + lane;

  f32x4 acc0 = {0.f, 0.f, 0.f, 0.f};
  f32x4 acc1 = acc0, acc2 = acc0, acc3 = acc0;

  for (int g = 0; g < 32; g += 4) {
    f32x4  a[4][2];
    bf16x8 bb[4][4];
#pragma unroll
    for (int qq = 0; qq < 4; ++qq) {
      a[qq][0] = *(const f32x4*)(arow + (g + qq) * 32);
      a[qq][1] = *(const f32x4*)(arow + (g + qq) * 32 + 4);
#pragma unroll
      for (int f = 0; f < 4; ++f) bb[qq][f] = bptr[((g + qq) * 4 + f) * 64];
    }
#pragma unroll
    for (int qq = 0; qq < 4; ++qq) {
      bf16x8 af = pack_bf16x8(a[qq][0], a[qq][1]);
      acc0 = __builtin_amdgcn_mfma_f32_16x16x32_bf16(af, bb[qq][0], acc0, 0, 0, 0);
      acc1 = __builtin_amdgcn_mfma_f32_16x16x32_bf16(af, bb[qq][1], acc1, 0, 0, 0);
      acc2 = __builtin_amdgcn_mfma_f32_16x16x32_bf16(af, bb[qq][2], acc2, 0, 0, 0);
      acc3 = __builtin_amdgcn_mfma_f32_16x16x32_bf16(af, bb[qq][3], acc3, 0, 0, 0);
    }
  }

  const float bv0 = bias[m], bv1 = bias[16 + m], bv2 = bias[32 + m], bv3 = bias[48 + m];
  float* op = xbuf + (size_t)(r0 + kg * 4) * NT + m;
#pragma unroll
  for (int r = 0; r < 4; ++r) {
    op[r * NT +  0] = __expf(acc0[r] + bv0);
    op[r * NT + 16] = __expf(acc1[r] + bv1);
    op[r * NT + 32] = __expf(acc2[r] + bv2);
    op[r * NT + 48] = __expf(acc3[r] + bv3);
  }
}

// ---------------------------------------------------------------------------
// Kernel 2 (stage A): per-(batch,chunk) product matrix.
//   G_k = ( Π_{t in chunk, 1<=t<L} diag(x_t)·E·2^-6 )^T, computed as 16 steps
//   of G <- E'^T·(x ⊙_rows G) starting from I. One WG per (b,k); 4 waves, one
//   16-column tile each (columns never mix). E'^T resident as bf16 hi+lo
//   A-frags (precision split). Per-step D->B conversion = R2-validated
//   cvt_pk + permlane swap sequence. Output: Gout[b][k][j][i] bf16 row-major
//   (row j = dest tag, col i = source tag), via LDS transpose.
// ---------------------------------------------------------------------------
__global__ __launch_bounds__(256) void chunk_prod(const float* __restrict__ xbuf,
                                                  const float* __restrict__ trans,
                                                  const int*   __restrict__ seq_lens,
                                                  unsigned short* __restrict__ Gout) {
  __shared__ float lds[64 * 68];
  const int b   = blockIdx.x >> 4;
  const int k   = blockIdx.x & 15;
  const int tid = threadIdx.x;
  const int nt  = tid >> 6;           // wave id = column tile
  const int l   = tid & 63;
  const int q   = l >> 4, c = l & 15;

  const int L = seq_lens[b];          // in [2,256]

  // ---- E'^T fragments (A-operand), hi+lo bf16 split, scaled by 2^-6 ----
  bf16x8 eth[4][2], etl[4][2];
#pragma unroll
  for (int mt = 0; mt < 4; ++mt)
#pragma unroll
    for (int kf = 0; kf < 2; ++kf) {
      float vh[8], vl[8];
#pragma unroll
      for (int e = 0; e < 8; ++e) {
        float ef = __expf(trans[(32 * kf + 8 * q + e) * NT + 16 * mt + c]) * 0.015625f;
        u32 ub = __float_as_uint(ef);
        u32 hb = (ub + 0x7FFFu + ((ub >> 16) & 1u)) & 0xFFFF0000u;   // RNE to bf16
        vh[e] = __uint_as_float(hb);
        vl[e] = ef - vh[e];
      }
      union { u32 u[4]; bf16x8 v; } rh, rl;
      rh.u[0] = cvt_pk_bf16(vh[0], vh[1]); rh.u[1] = cvt_pk_bf16(vh[2], vh[3]);
      rh.u[2] = cvt_pk_bf16(vh[4], vh[5]); rh.u[3] = cvt_pk_bf16(vh[6], vh[7]);
      rl.u[0] = cvt_pk_bf16(vl[0], vl[1]); rl.u[1] = cvt_pk_bf16(vl[2], vl[3]);
      rl.u[2] = cvt_pk_bf16(vl[4], vl[5]); rl.u[3] = cvt_pk_bf16(vl[6], vl[7]);
      eth[mt][kf] = rh.v; etl[mt][kf] = rl.v;
    }

  // ---- G = I (this wave's column tile): G[16mt+4q+r][16nt+c] ----
  f32x4 g[4];
#pragma unroll
  for (int mt = 0; mt < 4; ++mt) {
    f32x4 z = {0.f, 0.f, 0.f, 0.f};
    int r = c - 4 * q;
    if (mt == nt && r >= 0 && r < 4) z[r] = 1.0f;
    g[mt] = z;
  }

  int tbeg = 16 * k; if (tbeg < 1) tbeg = 1;
  int tend = 16 * k + 16; if (tend > L) tend = L;

  const float* xb = xbuf + (size_t)b * NT + 4 * q;  // + t*4096 + 16*mt

#define SWAPQ(A, B) do {                                                  \
    asm("v_permlane32_swap_b32 %0, %1" : "+v"(A), "+v"(B));               \
    asm("v_permlane16_swap_b32 %0, %1" : "+v"(A), "+v"(B));               \
  } while (0)

  if (tbeg < tend) {
    f32x4 xs[4], xn[4];
#pragma unroll
    for (int mt = 0; mt < 4; ++mt)
      xs[mt] = *(const f32x4*)(xb + (size_t)tbeg * (NB * NT) + 16 * mt);

    for (int t = tbeg; t < tend; ++t) {
      // prefetch next step's x (t+1 <= 256; xbuf has slack rows)
#pragma unroll
      for (int mt = 0; mt < 4; ++mt)
        xn[mt] = *(const f32x4*)(xb + (size_t)(t + 1) * (NB * NT) + 16 * mt);

      u32 p[4][2];
#pragma unroll
      for (int mt = 0; mt < 4; ++mt) {
        f32x4 w = g[mt] * xs[mt];             // row-scale by x (rows = src tags)
        p[mt][0] = cvt_pk_bf16(w.x, w.y);
        p[mt][1] = cvt_pk_bf16(w.z, w.w);
      }
      SWAPQ(p[0][0], p[1][0]); SWAPQ(p[0][1], p[1][1]);
      SWAPQ(p[2][0], p[3][0]); SWAPQ(p[2][1], p[3][1]);
      union { u32 u[4]; bf16x8 v; } B0, B1;
      B0.u[0] = p[0][0]; B0.u[1] = p[0][1]; B0.u[2] = p[1][0]; B0.u[3] = p[1][1];
      B1.u[0] = p[2][0]; B1.u[1] = p[2][1]; B1.u[2] = p[3][0]; B1.u[3] = p[3][1];

      const f32x4 zz = {0.f, 0.f, 0.f, 0.f};
#pragma unroll
      for (int mt = 0; mt < 4; ++mt) {
        f32x4 d;
        d = __builtin_amdgcn_mfma_f32_16x16x32_bf16(eth[mt][0], B0.v, zz, 0, 0, 0);
        d = __builtin_amdgcn_mfma_f32_16x16x32_bf16(eth[mt][1], B1.v, d,  0, 0, 0);
        d = __builtin_amdgcn_mfma_f32_16x16x32_bf16(etl[mt][0], B0.v, d,  0, 0, 0);
        g[mt] = __builtin_amdgcn_mfma_f32_16x16x32_bf16(etl[mt][1], B1.v, d, 0, 0, 0);
      }
#pragma unroll
      for (int mt = 0; mt < 4; ++mt) xs[mt] = xn[mt];
    }
  }
#undef SWAPQ

  // ---- transpose via LDS, pack bf16, store row-major ----
#pragma unroll
  for (int mt = 0; mt < 4; ++mt)
#pragma unroll
    for (int r = 0; r < 4; ++r)
      lds[(16 * mt + 4 * q + r) * 68 + 16 * nt + c] = g[mt][r];
  __syncthreads();
  {
    int row = tid >> 2, qt = tid & 3;
    const float* src = lds + row * 68 + qt * 16;
    u32 w[8];
#pragma unroll
    for (int m = 0; m < 8; ++m) w[m] = cvt_pk_bf16(src[2 * m], src[2 * m + 1]);
    u32x4* dst = (u32x4*)(Gout + (((size_t)(b * 16 + k) * 64 + row) * 64 + qt * 16));
    dst[0] = *(u32x4*)&w[0];
    dst[1] = *(u32x4*)&w[4];
  }
}

// ---------------------------------------------------------------------------
// Kernel 3 (stage B): per-batch combine. alpha (f32, lane j = tag j) through
// 16 chunk matrices: A'_j = sum_i A_i * Gk[j][i]; logZ += 6*ln2*n_k + pow2
// renorm. Also computes the exact gold path score. 64 blocks x 64 lanes.
// ---------------------------------------------------------------------------
__global__ __launch_bounds__(64) void chain_apply(const float* __restrict__ xbuf,
                                                  const float* __restrict__ trans,
                                                  const unsigned short* __restrict__ Gout,
                                                  const int*   __restrict__ tags,
                                                  const int*   __restrict__ seq_lens,
                                                  float* __restrict__ partials) {
  __shared__ __align__(16) float elds[64];
  const int b = blockIdx.x;
  const int j = threadIdx.x;
  const int L = seq_lens[b];

  // ---- gold path score ----
  float gold = 0.f;
  for (int s = j; s < L; s += 64) {
    int tg = tags[s * NB + b];
    int nx = (s + 1 < SLEN) ? tags[(s + 1) * NB + b] : 2;
    gold += __logf(xbuf[(size_t)(s * NB + b) * NT + tg]) + trans[tg * NT + nx];
  }
#pragma unroll
  for (int off = 32; off; off >>= 1) gold += __shfl_xor(gold, off, 64);

  // ---- alpha_0, logZ ----
  float A    = __expf(trans[j]);                    // trans[BOS][j]
  float logZ = __logf(xbuf[(size_t)b * NT]);        // emit[0,b,BOS]

  const unsigned short* gbase = Gout + (size_t)b * 16 * 4096 + (size_t)j * 64;
  u32x4 gc[8], gn[8];
#pragma unroll
  for (int m = 0; m < 8; ++m) gc[m] = *((const u32x4*)gbase + m);

  const float C6 = 6.f * 0.6931471805599453f;

  for (int k = 0; k < 16; ++k) {
    if (k < 15) {
      const u32x4* gb2 = (const u32x4*)(gbase + (size_t)(k + 1) * 4096);
#pragma unroll
      for (int m = 0; m < 8; ++m) gn[m] = gb2[m];
    }
    int tb = 16 * k; if (tb < 1) tb = 1;
    int te = 16 * k + 16; if (te > L) te = L;
    int n = te - tb;
    if (n > 0) {
      elds[j] = A;                    // same-wave DS ordering (R1-proven)
      float s0 = 0.f, s1 = 0.f, s2 = 0.f, s3 = 0.f;
#pragma unroll
      for (int m = 0; m < 8; ++m) {
        f32x4 av0 = *(const f32x4*)(elds + 8 * m);
        f32x4 av1 = *(const f32x4*)(elds + 8 * m + 4);
        u32x4 w = gc[m];
        s0 = fmaf(av0.x, __uint_as_float(w.x << 16),        s0);
        s1 = fmaf(av0.y, __uint_as_float(w.x & 0xFFFF0000u), s1);
        s2 = fmaf(av0.z, __uint_as_float(w.y << 16),        s2);
        s3 = fmaf(av0.w, __uint_as_float(w.y & 0xFFFF0000u), s3);
        s0 = fmaf(av1.x, __uint_as_float(w.z << 16),        s0);
        s1 = fmaf(av1.y, __uint_as_float(w.z & 0xFFFF0000u), s1);
        s2 = fmaf(av1.z, __uint_as_float(w.w << 16),        s2);
        s3 = fmaf(av1.w, __uint_as_float(w.w & 0xFFFF0000u), s3);
      }
      A = (s0 + s1) + (s2 + s3);
      logZ += C6 * (float)n;
      // pow2 renorm (batch-uniform, exact)
      u32 bb = __builtin_amdgcn_readfirstlane(__float_as_uint(A));
      int ex = (int)((bb >> 23) & 255u) - 127;
      A *= __uint_as_float((u32)(127 - ex) << 23);
      logZ += (float)ex * 0.6931471805599453f;
    }
    if (k < 15) {
#pragma unroll
      for (int m = 0; m < 8; ++m) gc[m] = gn[m];
    }
  }

  float res = logZ + __logf(A);
  res = __shfl(res, 1, 64);           // EOS = 1
  if (j == 0) partials[b] = res - gold;
}

// ---------------------------------------------------------------------------
// Kernel 4: out[0] = sum_b partials[b]
// ---------------------------------------------------------------------------
__global__ __launch_bounds__(64) void final_reduce(const float* __restrict__ partials,
                                                   float* __restrict__ out) {
  float v = partials[threadIdx.x];
#pragma unroll
  for (int off = 32; off; off >>= 1) v += __shfl_xor(v, off, 64);
  if (threadIdx.x == 0) out[0] = v;
}

extern "C" void kernel_launch(void* const* d_in, const int* in_sizes, int n_in,
                              void* d_out, int out_size, void* d_ws, size_t ws_size,
                              hipStream_t stream) {
  const float* F     = (const float*)d_in[0];   // features (S,B,D) f32
  const int*   tags  = (const int*)  d_in[1];   // (S,B) i32
  const int*   seq   = (const int*)  d_in[2];   // (B,) i32
  const float* W     = (const float*)d_in[3];   // (T,D) f32
  const float* bias  = (const float*)d_in[4];   // (T,) f32
  const float* trans = (const float*)d_in[5];   // (T,T) f32
  float* out = (float*)d_out;

  char* ws = (char*)d_ws;
  // xbuf: 256 rows used + prefetch slack (272 rows)          @ 0        (4,456,448 B)
  // Wb3  : 128 KiB                                           @ 4456448
  // Gout : 64 b x 16 k x 64 x 64 bf16 = 8 MiB                @ 4587520
  // partials: 256 B                                          @ 12976128
  float*          xbuf     = (float*)ws;
  unsigned short* Wb3      = (unsigned short*)(ws + 4456448);
  unsigned short* Gout     = (unsigned short*)(ws + 4587520);
  float*          partials = (float*)(ws + 12976128);

  prep_w      <<<256,  256, 0, stream>>>(W, Wb3);
  emit_gemm   <<<256,  256, 0, stream>>>(F, Wb3, bias, xbuf);
  chunk_prod  <<<1024, 256, 0, stream>>>(xbuf, trans, seq, Gout);
  chain_apply <<<64,    64, 0, stream>>>(xbuf, trans, Gout, tags, seq, partials);
  final_reduce<<<1,     64, 0, stream>>>(partials, out);
}